// Round 9
// baseline (330.280 us; speedup 1.0000x reference)
//
#include <hip/hip_runtime.h>
#include <hip/hip_fp16.h>

using uint = unsigned int;

static constexpr int NN  = 100000;   // nodes
static constexpr int NE  = 1600000;  // edges per set
static constexpr int DIM = 64;
static constexpr int HH  = 32;
static constexpr int NBLK = (NN + 255) / 256;   // 391 node-blocks
static constexpr int HB   = 1024;               // partition blocks per edge set
static constexpr int CHUNK = (NE + HB - 1) / HB;  // 1563
static constexpr int BSH  = 8;                  // bucket = dst >> 8 (256 nodes/bucket)
static constexpr int BSZ  = 256;
static constexpr int NBKT = (NN + BSZ - 1) / BSZ;  // 391 live buckets (of 512 bins)

__device__ __forceinline__ float2 up16(uint v) {
  __half2 h = *reinterpret_cast<__half2*>(&v);
  return __half22float2(h);
}
__device__ __forceinline__ uint pk16(float a, float b) {
  __half2 h = __floats2half2_rn(a, b);
  return *reinterpret_cast<uint*>(&h);
}

// ================= atomic-free CSR build (radix partition by dst>>8) =================

// A1: per-block 512-bin histogram. part_hist[set][b][bin]
__global__ void c_hist(const int* __restrict__ pe, const int* __restrict__ ne,
                       int* __restrict__ part_hist) {
  const int set = blockIdx.y;
  const int* dstA = (set ? ne : pe) + NE;
  __shared__ int h[512];
  h[threadIdx.x] = 0; h[threadIdx.x + 256] = 0;
  __syncthreads();
  int lo = blockIdx.x * CHUNK;
  int hi = min(lo + CHUNK, NE);
  for (int i = lo + threadIdx.x; i < hi; i += 256)
    atomicAdd(&h[dstA[i] >> BSH], 1);
  __syncthreads();
  int* o = part_hist + (size_t)(set * HB + blockIdx.x) * 512;
  o[threadIdx.x] = h[threadIdx.x];
  o[threadIdx.x + 256] = h[threadIdx.x + 256];
}

// A2: per (set,bin): exclusive scan over the HB block-partials (in place); total->tot.
__global__ void c_colscan(int* __restrict__ part_hist, int* __restrict__ tot) {
  const int set = blockIdx.y;
  const int k   = blockIdx.x;   // bin 0..511
  const int t   = threadIdx.x;  // block b (0..HB-1), 1024 threads
  int v = part_hist[(size_t)(set * HB + t) * 512 + k];
  __shared__ int sm[HB];
  sm[t] = v;
  __syncthreads();
  for (int off = 1; off < HB; off <<= 1) {
    int add = (t >= off) ? sm[t - off] : 0;
    __syncthreads();
    sm[t] += add;
    __syncthreads();
  }
  part_hist[(size_t)(set * HB + t) * 512 + k] = (t == 0) ? 0 : sm[t - 1];
  if (t == HB - 1) tot[set * 512 + k] = sm[HB - 1];
}

// A3: one block, 1024 threads: exclusive scan of 512 bins per set -> base[set][0..512]
__global__ void c_basescan(const int* __restrict__ tot, int* __restrict__ base) {
  const int t   = threadIdx.x;
  const int seg = t >> 9;      // set
  const int idx = t & 511;     // bin
  int v = tot[seg * 512 + idx];
  __shared__ int sm[1024];
  sm[t] = v;
  __syncthreads();
  for (int off = 1; off < 512; off <<= 1) {
    int add = (idx >= off) ? sm[t - off] : 0;
    __syncthreads();
    sm[t] += add;
    __syncthreads();
  }
  base[seg * 513 + idx] = (idx == 0) ? 0 : sm[t - 1];
  if (idx == 511) base[seg * 513 + 512] = sm[t];   // == NE
}

// A4: scatter packed (src<<8 | dst&255) into bucket-partitioned order.
// LDS counters start at the block's reserved absolute offset per bin -> no global atomics.
__global__ void c_scatter(const int* __restrict__ pe, const int* __restrict__ ne,
                          const int* __restrict__ part_hist, const int* __restrict__ base,
                          uint* __restrict__ partP, uint* __restrict__ partN) {
  const int set = blockIdx.y;
  const int b   = blockIdx.x;
  const int* srcA = set ? ne : pe;
  const int* dstA = srcA + NE;
  uint* part = set ? partN : partP;
  __shared__ int off[512];
  const int* ph = part_hist + (size_t)(set * HB + b) * 512;
  off[threadIdx.x]       = base[set * 513 + threadIdx.x]       + ph[threadIdx.x];
  off[threadIdx.x + 256] = base[set * 513 + threadIdx.x + 256] + ph[threadIdx.x + 256];
  __syncthreads();
  int lo = b * CHUNK;
  int hi = min(lo + CHUNK, NE);
  for (int i = lo + threadIdx.x; i < hi; i += 256) {
    int src = srcA[i];
    int dst = dstA[i];
    int pos = atomicAdd(&off[dst >> BSH], 1);
    part[pos] = ((uint)src << BSH) | (uint)(dst & (BSZ - 1));
  }
}

// B: per-bucket CSR (LDS count -> LDS scan -> rowptr + col scatter). Pure, 3KB LDS.
__global__ void c_bucket(const uint* __restrict__ partP, const uint* __restrict__ partN,
                         const int* __restrict__ base,
                         int* __restrict__ row_p, int* __restrict__ row_n,
                         int* __restrict__ col_p, int* __restrict__ col_n) {
  const int bx = blockIdx.x;            // [0, 2*NBKT)
  const int t  = threadIdx.x;
  const int set = (bx >= NBKT) ? 1 : 0;
  const int k   = bx - (set ? NBKT : 0);
  const uint* part = set ? partN : partP;
  int* row = set ? row_n : row_p;
  int* col = set ? col_n : col_p;
  const int lo = k * BSZ;
  const int hi = min(lo + BSZ, NN);
  const int s = base[set * 513 + k];
  const int e = base[set * 513 + k + 1];

  __shared__ int cnt[BSZ], rowl[BSZ], cnt2[BSZ];
  cnt[t] = 0; cnt2[t] = 0;
  __syncthreads();
  for (int i = s + t; i < e; i += 256)
    atomicAdd(&cnt[part[i] & (BSZ - 1)], 1);
  __syncthreads();
  rowl[t] = cnt[t];
  __syncthreads();
  for (int off = 1; off < BSZ; off <<= 1) {
    int a0 = (t >= off) ? rowl[t - off] : 0;
    __syncthreads();
    rowl[t] += a0;
    __syncthreads();
  }
  if (lo + t < hi) row[lo + t] = s + (t ? rowl[t - 1] : 0);
  if (k == NBKT - 1 && t == 0) row[NN] = NE;
  for (int i = s + t; i < e; i += 256) {
    uint p = part[i];
    int l = p & (BSZ - 1);
    int pos = s + (l ? rowl[l - 1] : 0) + atomicAdd(&cnt2[l], 1);
    col[pos] = (int)(p >> BSH);
  }
}

// ---------------- layer-1 pre-transform (standalone; full occupancy) ----------------
// y1{p,n}[node] = x@wl (f16, 64B row); r1 = x@wr + b (f32, in d_out)
__global__ void k_pre1(const float* __restrict__ x,
                       const float* __restrict__ w1_pl, const float* __restrict__ w1_pr,
                       const float* __restrict__ b1_p,
                       const float* __restrict__ w1_nl, const float* __restrict__ w1_nr,
                       const float* __restrict__ b1_n,
                       uint* __restrict__ y1p, uint* __restrict__ y1n,
                       float* __restrict__ r1) {
  const int h = blockIdx.y;
  const float* wl   = h ? w1_nl : w1_pl;  // [64][32]
  const float* wr   = h ? w1_nr : w1_pr;  // [64][32]
  const float* bias = h ? b1_n  : b1_p;

  __shared__ float s_wl[DIM * HH];
  __shared__ float s_wr[DIM * HH];
  for (int i = threadIdx.x; i < DIM * HH; i += 256) {
    s_wl[i] = wl[i];
    s_wr[i] = wr[i];
  }
  __syncthreads();

  int node = blockIdx.x * 256 + threadIdx.x;
  if (node >= NN) return;

  float ay[HH], ar[HH];
#pragma unroll
  for (int j = 0; j < HH; ++j) { ay[j] = 0.f; ar[j] = bias[j]; }

  const float4* xrow = (const float4*)(x + (size_t)node * DIM);
#pragma unroll 4
  for (int k4 = 0; k4 < DIM / 4; ++k4) {
    float4 xv = xrow[k4];
#pragma unroll
    for (int u = 0; u < 4; ++u) {
      int k = k4 * 4 + u;
      float xk = (&xv.x)[u];
#pragma unroll
      for (int j = 0; j < HH; ++j) {
        ay[j] += xk * s_wl[k * HH + j];
        ar[j] += xk * s_wr[k * HH + j];
      }
    }
  }

  uint*  yo = (h ? y1n : y1p) + (size_t)node * 16;
  float* ro = r1 + (size_t)node * 64 + h * 32;
#pragma unroll
  for (int j = 0; j < 16; ++j) yo[j] = pk16(ay[2 * j], ay[2 * j + 1]);
#pragma unroll
  for (int j = 0; j < HH; ++j) ro[j] = ar[j];
}

// ---------------- aggregation 1 (16 edges/iter, uint4 per lane, split tables) --------
// y1p/y1n rows = 16 uints (32 f16). lane = (g,f): g=lane>>2 (16 edge slots), f=lane&3.
// Lane loads uint4 = features 8f..8f+7. Butterfly xor 4..32 sums over g.
// NOTE: r1 and z ALIAS (both d_out): same-thread read-then-write only.
__global__ void k_aggr1(const uint* __restrict__ y1p, const uint* __restrict__ y1n,
                        const int* __restrict__ rp, const int* __restrict__ cp,
                        const int* __restrict__ rn, const int* __restrict__ cn,
                        const float* r1,
                        float* z) {
  int gid  = blockIdx.x * 256 + threadIdx.x;
  int node = gid >> 6;
  if (node >= NN) return;
  int lane = threadIdx.x & 63;
  int g = lane >> 2;      // edge slot 0..15
  int f = lane & 3;       // uint4 index

  int s = rp[node], e = rp[node + 1];
  float a[8];
#pragma unroll
  for (int j = 0; j < 8; ++j) a[j] = 0.f;
  for (int i = s + g; i < e; i += 16) {
    int c = cp[i];
    uint4 v = *(const uint4*)&y1p[(size_t)c * 16 + 4 * f];
    float2 p0 = up16(v.x), p1 = up16(v.y), p2 = up16(v.z), p3 = up16(v.w);
    a[0] += p0.x; a[1] += p0.y; a[2] += p1.x; a[3] += p1.y;
    a[4] += p2.x; a[5] += p2.y; a[6] += p3.x; a[7] += p3.y;
  }
#pragma unroll
  for (int w = 4; w <= 32; w <<= 1) {
#pragma unroll
    for (int j = 0; j < 8; ++j) a[j] += __shfl_xor(a[j], w);
  }
  float invp = 1.f / (float)max(e - s, 1);

  s = rn[node]; e = rn[node + 1];
  float b[8];
#pragma unroll
  for (int j = 0; j < 8; ++j) b[j] = 0.f;
  for (int i = s + g; i < e; i += 16) {
    int c = cn[i];
    uint4 v = *(const uint4*)&y1n[(size_t)c * 16 + 4 * f];
    float2 p0 = up16(v.x), p1 = up16(v.y), p2 = up16(v.z), p3 = up16(v.w);
    b[0] += p0.x; b[1] += p0.y; b[2] += p1.x; b[3] += p1.y;
    b[4] += p2.x; b[5] += p2.y; b[6] += p3.x; b[7] += p3.y;
  }
#pragma unroll
  for (int w = 4; w <= 32; w <<= 1) {
#pragma unroll
    for (int j = 0; j < 8; ++j) b[j] += __shfl_xor(b[j], w);
  }
  float invn = 1.f / (float)max(e - s, 1);

  size_t base = (size_t)node * 64;
  if (g == 0) {
    const float4 r0 = *(const float4*)(r1 + base + 8 * f);
    const float4 r1v = *(const float4*)(r1 + base + 8 * f + 4);
    float4 o0, o1;
    o0.x = fmaxf(a[0] * invp + r0.x, 0.f);
    o0.y = fmaxf(a[1] * invp + r0.y, 0.f);
    o0.z = fmaxf(a[2] * invp + r0.z, 0.f);
    o0.w = fmaxf(a[3] * invp + r0.w, 0.f);
    o1.x = fmaxf(a[4] * invp + r1v.x, 0.f);
    o1.y = fmaxf(a[5] * invp + r1v.y, 0.f);
    o1.z = fmaxf(a[6] * invp + r1v.z, 0.f);
    o1.w = fmaxf(a[7] * invp + r1v.w, 0.f);
    *(float4*)(z + base + 8 * f) = o0;
    *(float4*)(z + base + 8 * f + 4) = o1;
  } else if (g == 1) {
    const float4 r0 = *(const float4*)(r1 + base + 32 + 8 * f);
    const float4 r1v = *(const float4*)(r1 + base + 32 + 8 * f + 4);
    float4 o0, o1;
    o0.x = fmaxf(b[0] * invn + r0.x, 0.f);
    o0.y = fmaxf(b[1] * invn + r0.y, 0.f);
    o0.z = fmaxf(b[2] * invn + r0.z, 0.f);
    o0.w = fmaxf(b[3] * invn + r0.w, 0.f);
    o1.x = fmaxf(b[4] * invn + r1v.x, 0.f);
    o1.y = fmaxf(b[5] * invn + r1v.y, 0.f);
    o1.z = fmaxf(b[6] * invn + r1v.z, 0.f);
    o1.w = fmaxf(b[7] * invn + r1v.w, 0.f);
    *(float4*)(z + base + 32 + 8 * f) = o0;
    *(float4*)(z + base + 32 + 8 * f + 4) = o1;
  }
}

// ---------------- pre-transform layer 2 ----------------
__global__ void k_mid(const float* __restrict__ z,
                      const float* __restrict__ w2_pl, const float* __restrict__ w2_pr,
                      const float* __restrict__ b2_p,
                      const float* __restrict__ w2_nl, const float* __restrict__ w2_nr,
                      const float* __restrict__ b2_n,
                      uint* __restrict__ u_pos, uint* __restrict__ u_neg,
                      float* __restrict__ r2) {
  const int t = blockIdx.y;
  const float* mat;
  const float* bias = nullptr;
  int srcHalf;            // 0 = zp, 1 = zn
  switch (t) {
    case 0: mat = w2_pl;            srcHalf = 0; break;
    case 1: mat = w2_nl;            srcHalf = 1; break;
    case 2: mat = w2_pl + 32 * 32;  srcHalf = 1; break;
    case 3: mat = w2_nl + 32 * 32;  srcHalf = 0; break;
    case 4: mat = w2_pr; bias = b2_p; srcHalf = 0; break;
    default: mat = w2_nr; bias = b2_n; srcHalf = 1; break;
  }

  __shared__ float s_m[HH][HH];
  for (int i = threadIdx.x; i < HH * HH; i += 256) s_m[i >> 5][i & 31] = mat[i];
  __syncthreads();

  int node = blockIdx.x * 256 + threadIdx.x;
  if (node >= NN) return;

  float acc[HH];
#pragma unroll
  for (int j = 0; j < HH; ++j) acc[j] = bias ? bias[j] : 0.f;

  const float4* zrow = (const float4*)(z + (size_t)node * 64 + srcHalf * 32);
#pragma unroll 4
  for (int k4 = 0; k4 < HH / 4; ++k4) {
    float4 v = zrow[k4];
#pragma unroll
    for (int u = 0; u < 4; ++u) {
      int k = k4 * 4 + u;
      float vv = (&v.x)[u];
#pragma unroll
      for (int j = 0; j < HH; ++j) acc[j] += vv * s_m[k][j];
    }
  }

  if (t < 4) {
    uint* o = (t < 2 ? u_pos : u_neg) + (size_t)node * 32 + (t & 1) * 16;
#pragma unroll
    for (int j = 0; j < 16; ++j) o[j] = pk16(acc[2 * j], acc[2 * j + 1]);
  } else {
    float* o = r2 + (size_t)node * 64 + (t - 4) * 32;
#pragma unroll
    for (int j = 0; j < HH; ++j) o[j] = acc[j];
  }
}

// ---------------- aggregation 2 (8 edges/iter, uint4 per lane) ----------------
__global__ void k_aggr2(const uint* __restrict__ u_pos, const uint* __restrict__ u_neg,
                        const int* __restrict__ rp, const int* __restrict__ cp,
                        const int* __restrict__ rn, const int* __restrict__ cn,
                        const float* __restrict__ r2,
                        float* __restrict__ out) {
  int gid  = blockIdx.x * 256 + threadIdx.x;
  int node = gid >> 6;
  if (node >= NN) return;
  int lane = threadIdx.x & 63;
  int g = lane >> 3;      // edge slot 0..7
  int f = lane & 7;       // uint4 index in row

  int s = rp[node], e = rp[node + 1];
  float a[8];
#pragma unroll
  for (int j = 0; j < 8; ++j) a[j] = 0.f;
  for (int i = s + g; i < e; i += 8) {
    int c = cp[i];
    uint4 v = *(const uint4*)&u_pos[(size_t)c * 32 + 4 * f];
    float2 p0 = up16(v.x), p1 = up16(v.y), p2 = up16(v.z), p3 = up16(v.w);
    a[0] += p0.x; a[1] += p0.y; a[2] += p1.x; a[3] += p1.y;
    a[4] += p2.x; a[5] += p2.y; a[6] += p3.x; a[7] += p3.y;
  }
#pragma unroll
  for (int w = 8; w <= 32; w <<= 1) {
#pragma unroll
    for (int j = 0; j < 8; ++j) a[j] += __shfl_xor(a[j], w);
  }
  float invp = 1.f / (float)max(e - s, 1);

  s = rn[node]; e = rn[node + 1];
  float b[8];
#pragma unroll
  for (int j = 0; j < 8; ++j) b[j] = 0.f;
  for (int i = s + g; i < e; i += 8) {
    int c = cn[i];
    uint4 v = *(const uint4*)&u_neg[(size_t)c * 32 + 4 * f];
    float2 p0 = up16(v.x), p1 = up16(v.y), p2 = up16(v.z), p3 = up16(v.w);
    b[0] += p0.x; b[1] += p0.y; b[2] += p1.x; b[3] += p1.y;
    b[4] += p2.x; b[5] += p2.y; b[6] += p3.x; b[7] += p3.y;
  }
#pragma unroll
  for (int w = 8; w <= 32; w <<= 1) {
#pragma unroll
    for (int j = 0; j < 8; ++j) b[j] += __shfl_xor(b[j], w);
  }
  float invn = 1.f / (float)max(e - s, 1);

  if (g == 0) {
    size_t base = (size_t)node * 64 + 8 * f;
    const float4 r0 = *(const float4*)(r2 + base);
    const float4 r1v = *(const float4*)(r2 + base + 4);
    float4 o0, o1;
    o0.x = fmaxf(a[0] * invp + b[0] * invn + r0.x, 0.f);
    o0.y = fmaxf(a[1] * invp + b[1] * invn + r0.y, 0.f);
    o0.z = fmaxf(a[2] * invp + b[2] * invn + r0.z, 0.f);
    o0.w = fmaxf(a[3] * invp + b[3] * invn + r0.w, 0.f);
    o1.x = fmaxf(a[4] * invp + b[4] * invn + r1v.x, 0.f);
    o1.y = fmaxf(a[5] * invp + b[5] * invn + r1v.y, 0.f);
    o1.z = fmaxf(a[6] * invp + b[6] * invn + r1v.z, 0.f);
    o1.w = fmaxf(a[7] * invp + b[7] * invn + r1v.w, 0.f);
    *(float4*)(out + base) = o0;
    *(float4*)(out + base + 4) = o1;
  }
}

// ---------------- launch ----------------

extern "C" void kernel_launch(void* const* d_in, const int* in_sizes, int n_in,
                              void* d_out, int out_size, void* d_ws, size_t ws_size,
                              hipStream_t stream) {
  const float* x     = (const float*)d_in[0];
  const int*   pe    = (const int*)d_in[1];
  const int*   ne    = (const int*)d_in[2];
  const float* w1_pl = (const float*)d_in[3];
  const float* w1_pr = (const float*)d_in[4];
  const float* b1_p  = (const float*)d_in[5];
  const float* w1_nl = (const float*)d_in[6];
  const float* w1_nr = (const float*)d_in[7];
  const float* b1_n  = (const float*)d_in[8];
  const float* w2_pl = (const float*)d_in[9];
  const float* w2_pr = (const float*)d_in[10];
  const float* b2_p  = (const float*)d_in[11];
  const float* w2_nl = (const float*)d_in[12];
  const float* w2_nr = (const float*)d_in[13];
  const float* b2_n  = (const float*)d_in[14];

  char* ws = (char*)d_ws;
  size_t off = 0;
  auto alloc = [&](size_t bytes) -> char* {
    char* p = ws + off;
    off = (off + bytes + 255) & ~(size_t)255;
    return p;
  };

  int* row_p = (int*)alloc((size_t)(NN + 1) * 4);
  int* row_n = (int*)alloc((size_t)(NN + 1) * 4);
  int* col_p = (int*)alloc((size_t)NE * 4);
  int* col_n = (int*)alloc((size_t)NE * 4);
  int* tot   = (int*)alloc((size_t)2 * 512 * 4);
  int* base  = (int*)alloc((size_t)2 * 513 * 4);

  // union region A (25.6MB):
  //   CSR build phase: [partP 6.4MB][partN 6.4MB][part_hist 4MB][free]
  //   k_mid..k_aggr2:  [u_pos 12.8MB][u_neg 12.8MB]
  char* regA  = alloc((size_t)NN * 64 * 4);
  uint* partP = (uint*)regA;
  uint* partN = (uint*)(regA + (size_t)NE * 4);
  int*  part_hist = (int*)(regA + (size_t)2 * NE * 4);   // 2*HB*512*4 = 4MB
  uint* u_pos = (uint*)regA;
  uint* u_neg = (uint*)(regA + (size_t)NN * 32 * 4);

  // union region B (25.6MB): y1p+y1n (k_pre1..k_aggr1, 12.8MB) / r2 (k_mid..k_aggr2)
  char*  regB = alloc((size_t)NN * 64 * 4);
  uint*  y1p  = (uint*)regB;
  uint*  y1n  = (uint*)(regB + (size_t)NN * 16 * 4);
  float* r2   = (float*)regB;

  // r1 and z both live in d_out; k_aggr2 fully overwrites d_out at the end.
  float* r1 = (float*)d_out;
  float* z  = (float*)d_out;

  const int nb = NBLK;
  const int ab = (NN * 64 + 255) / 256;

  dim3 pg(nb, 2);
  k_pre1<<<pg, 256, 0, stream>>>(x, w1_pl, w1_pr, b1_p, w1_nl, w1_nr, b1_n,
                                 y1p, y1n, r1);

  dim3 hg(HB, 2);
  c_hist<<<hg, 256, 0, stream>>>(pe, ne, part_hist);
  dim3 cg(512, 2);
  c_colscan<<<cg, HB, 0, stream>>>(part_hist, tot);
  c_basescan<<<1, 1024, 0, stream>>>(tot, base);
  c_scatter<<<hg, 256, 0, stream>>>(pe, ne, part_hist, base, partP, partN);
  c_bucket<<<2 * NBKT, 256, 0, stream>>>(partP, partN, base,
                                         row_p, row_n, col_p, col_n);

  k_aggr1<<<ab, 256, 0, stream>>>(y1p, y1n, row_p, col_p, row_n, col_n, r1, z);

  dim3 g2(nb, 6);
  k_mid<<<g2, 256, 0, stream>>>(z, w2_pl, w2_pr, b2_p, w2_nl, w2_nr, b2_n,
                                u_pos, u_neg, r2);

  k_aggr2<<<ab, 256, 0, stream>>>(u_pos, u_neg, row_p, col_p, row_n, col_n, r2,
                                  (float*)d_out);
}

// Round 10
// 313.799 us; speedup vs baseline: 1.0525x; 1.0525x over previous
//
#include <hip/hip_runtime.h>
#include <hip/hip_fp16.h>

using uint = unsigned int;

static constexpr int NN  = 100000;   // nodes
static constexpr int NE  = 1600000;  // edges per set
static constexpr int DIM = 64;
static constexpr int HH  = 32;
static constexpr int NBLK = (NN + 255) / 256;   // 391 node-blocks
static constexpr int HB   = 512;                // histogram chunks per edge set
static constexpr int CHUNK = NE / HB;           // 3125 (exact)
static constexpr int SB   = 256;                // scatter blocks (2 chunks each)
static constexpr int BSH  = 8;                  // bucket = dst >> 8 (256 nodes/bucket)
static constexpr int BSZ  = 256;
static constexpr int NBKT = (NN + BSZ - 1) / BSZ;  // 391 live buckets (of 512 bins)

__device__ __forceinline__ float2 up16(uint v) {
  __half2 h = *reinterpret_cast<__half2*>(&v);
  return __half22float2(h);
}
__device__ __forceinline__ uint pk16(float a, float b) {
  __half2 h = __floats2half2_rn(a, b);
  return *reinterpret_cast<uint*>(&h);
}

// ================= atomic-free CSR build (radix partition by dst>>8) =================

// A1: per-chunk 512-bin histogram. part_hist[set][chunk][bin]
__global__ void c_hist(const int* __restrict__ pe, const int* __restrict__ ne,
                       int* __restrict__ part_hist) {
  const int set = blockIdx.y;
  const int* dstA = (set ? ne : pe) + NE;
  __shared__ int h[512];
  h[threadIdx.x] = 0; h[threadIdx.x + 256] = 0;
  __syncthreads();
  int lo = blockIdx.x * CHUNK;
  int hi = lo + CHUNK;
  for (int i = lo + threadIdx.x; i < hi; i += 256)
    atomicAdd(&h[dstA[i] >> BSH], 1);
  __syncthreads();
  int* o = part_hist + (size_t)(set * HB + blockIdx.x) * 512;
  o[threadIdx.x] = h[threadIdx.x];
  o[threadIdx.x + 256] = h[threadIdx.x + 256];
}

// A2: per (set,bin): exclusive scan over the HB chunk-partials (in place); total->tot.
__global__ void c_colscan(int* __restrict__ part_hist, int* __restrict__ tot) {
  const int set = blockIdx.y;
  const int k   = blockIdx.x;   // bin 0..511
  const int t   = threadIdx.x;  // chunk (0..HB-1), 512 threads
  int v = part_hist[(size_t)(set * HB + t) * 512 + k];
  __shared__ int sm[HB];
  sm[t] = v;
  __syncthreads();
  for (int off = 1; off < HB; off <<= 1) {
    int add = (t >= off) ? sm[t - off] : 0;
    __syncthreads();
    sm[t] += add;
    __syncthreads();
  }
  part_hist[(size_t)(set * HB + t) * 512 + k] = (t == 0) ? 0 : sm[t - 1];
  if (t == HB - 1) tot[set * 512 + k] = sm[HB - 1];
}

// A3: one block, 1024 threads: exclusive scan of 512 bins per set -> base[set][0..512]
__global__ void c_basescan(const int* __restrict__ tot, int* __restrict__ base) {
  const int t   = threadIdx.x;
  const int seg = t >> 9;      // set
  const int idx = t & 511;     // bin
  int v = tot[seg * 512 + idx];
  __shared__ int sm[1024];
  sm[t] = v;
  __syncthreads();
  for (int off = 1; off < 512; off <<= 1) {
    int add = (idx >= off) ? sm[t - off] : 0;
    __syncthreads();
    sm[t] += add;
    __syncthreads();
  }
  base[seg * 513 + idx] = (idx == 0) ? 0 : sm[t - 1];
  if (idx == 511) base[seg * 513 + 512] = sm[t];   // == NE
}

// A4: scatter packed (src<<8 | dst&255) into bucket-partitioned order.
// 512-thread blocks; block b consumes chunks {2b, 2b+1} (contiguous edge range).
// LDS counters start at chunk 2b's reserved offsets; consecutive chunks' per-bin
// reservations are contiguous, so one offset table covers both. No global atomics.
__global__ void c_scatter(const int* __restrict__ pe, const int* __restrict__ ne,
                          const int* __restrict__ part_hist, const int* __restrict__ base,
                          uint* __restrict__ partP, uint* __restrict__ partN) {
  const int set = blockIdx.y;
  const int b   = blockIdx.x;            // 0..SB-1
  const int t   = threadIdx.x;           // 0..511
  const int* srcA = set ? ne : pe;
  const int* dstA = srcA + NE;
  uint* part = set ? partN : partP;
  __shared__ int off[512];
  const int* ph = part_hist + (size_t)(set * HB + 2 * b) * 512;
  off[t] = base[set * 513 + t] + ph[t];
  __syncthreads();
  int lo = b * 2 * CHUNK;
  int hi = lo + 2 * CHUNK;               // NE = SB * 2 * CHUNK exactly
  for (int i = lo + t; i < hi; i += 512) {
    int src = srcA[i];
    int dst = dstA[i];
    int pos = atomicAdd(&off[dst >> BSH], 1);
    part[pos] = ((uint)src << BSH) | (uint)(dst & (BSZ - 1));
  }
}

// B: per-bucket CSR (LDS count -> LDS scan -> rowptr + col scatter). Pure, 3KB LDS.
__global__ void c_bucket(const uint* __restrict__ partP, const uint* __restrict__ partN,
                         const int* __restrict__ base,
                         int* __restrict__ row_p, int* __restrict__ row_n,
                         int* __restrict__ col_p, int* __restrict__ col_n) {
  const int bx = blockIdx.x;            // [0, 2*NBKT)
  const int t  = threadIdx.x;
  const int set = (bx >= NBKT) ? 1 : 0;
  const int k   = bx - (set ? NBKT : 0);
  const uint* part = set ? partN : partP;
  int* row = set ? row_n : row_p;
  int* col = set ? col_n : col_p;
  const int lo = k * BSZ;
  const int hi = min(lo + BSZ, NN);
  const int s = base[set * 513 + k];
  const int e = base[set * 513 + k + 1];

  __shared__ int cnt[BSZ], rowl[BSZ], cnt2[BSZ];
  cnt[t] = 0; cnt2[t] = 0;
  __syncthreads();
  for (int i = s + t; i < e; i += 256)
    atomicAdd(&cnt[part[i] & (BSZ - 1)], 1);
  __syncthreads();
  rowl[t] = cnt[t];
  __syncthreads();
  for (int off = 1; off < BSZ; off <<= 1) {
    int a0 = (t >= off) ? rowl[t - off] : 0;
    __syncthreads();
    rowl[t] += a0;
    __syncthreads();
  }
  if (lo + t < hi) row[lo + t] = s + (t ? rowl[t - 1] : 0);
  if (k == NBKT - 1 && t == 0) row[NN] = NE;
  for (int i = s + t; i < e; i += 256) {
    uint p = part[i];
    int l = p & (BSZ - 1);
    int pos = s + (l ? rowl[l - 1] : 0) + atomicAdd(&cnt2[l], 1);
    col[pos] = (int)(p >> BSH);
  }
}

// ---------------- layer-1 pre-transform (standalone; full occupancy) ----------------
// y1{p,n}[node] = x@wl (f16, 64B row); r1 = x@wr + b (f32, in d_out)
__global__ void k_pre1(const float* __restrict__ x,
                       const float* __restrict__ w1_pl, const float* __restrict__ w1_pr,
                       const float* __restrict__ b1_p,
                       const float* __restrict__ w1_nl, const float* __restrict__ w1_nr,
                       const float* __restrict__ b1_n,
                       uint* __restrict__ y1p, uint* __restrict__ y1n,
                       float* __restrict__ r1) {
  const int h = blockIdx.y;
  const float* wl   = h ? w1_nl : w1_pl;  // [64][32]
  const float* wr   = h ? w1_nr : w1_pr;  // [64][32]
  const float* bias = h ? b1_n  : b1_p;

  __shared__ float s_wl[DIM * HH];
  __shared__ float s_wr[DIM * HH];
  for (int i = threadIdx.x; i < DIM * HH; i += 256) {
    s_wl[i] = wl[i];
    s_wr[i] = wr[i];
  }
  __syncthreads();

  int node = blockIdx.x * 256 + threadIdx.x;
  if (node >= NN) return;

  float ay[HH], ar[HH];
#pragma unroll
  for (int j = 0; j < HH; ++j) { ay[j] = 0.f; ar[j] = bias[j]; }

  const float4* xrow = (const float4*)(x + (size_t)node * DIM);
#pragma unroll 4
  for (int k4 = 0; k4 < DIM / 4; ++k4) {
    float4 xv = xrow[k4];
#pragma unroll
    for (int u = 0; u < 4; ++u) {
      int k = k4 * 4 + u;
      float xk = (&xv.x)[u];
#pragma unroll
      for (int j = 0; j < HH; ++j) {
        ay[j] += xk * s_wl[k * HH + j];
        ar[j] += xk * s_wr[k * HH + j];
      }
    }
  }

  uint*  yo = (h ? y1n : y1p) + (size_t)node * 16;
  float* ro = r1 + (size_t)node * 64 + h * 32;
#pragma unroll
  for (int j = 0; j < 16; ++j) yo[j] = pk16(ay[2 * j], ay[2 * j + 1]);
#pragma unroll
  for (int j = 0; j < HH; ++j) ro[j] = ar[j];
}

// ---------------- aggregation 1 (16 edges/iter, uint4 per lane, split tables) --------
// NOTE: r1 and z ALIAS (both d_out): same-thread read-then-write only.
__global__ void k_aggr1(const uint* __restrict__ y1p, const uint* __restrict__ y1n,
                        const int* __restrict__ rp, const int* __restrict__ cp,
                        const int* __restrict__ rn, const int* __restrict__ cn,
                        const float* r1,
                        float* z) {
  int gid  = blockIdx.x * 256 + threadIdx.x;
  int node = gid >> 6;
  if (node >= NN) return;
  int lane = threadIdx.x & 63;
  int g = lane >> 2;      // edge slot 0..15
  int f = lane & 3;       // uint4 index

  int s = rp[node], e = rp[node + 1];
  float a[8];
#pragma unroll
  for (int j = 0; j < 8; ++j) a[j] = 0.f;
  for (int i = s + g; i < e; i += 16) {
    int c = cp[i];
    uint4 v = *(const uint4*)&y1p[(size_t)c * 16 + 4 * f];
    float2 p0 = up16(v.x), p1 = up16(v.y), p2 = up16(v.z), p3 = up16(v.w);
    a[0] += p0.x; a[1] += p0.y; a[2] += p1.x; a[3] += p1.y;
    a[4] += p2.x; a[5] += p2.y; a[6] += p3.x; a[7] += p3.y;
  }
#pragma unroll
  for (int w = 4; w <= 32; w <<= 1) {
#pragma unroll
    for (int j = 0; j < 8; ++j) a[j] += __shfl_xor(a[j], w);
  }
  float invp = 1.f / (float)max(e - s, 1);

  s = rn[node]; e = rn[node + 1];
  float b[8];
#pragma unroll
  for (int j = 0; j < 8; ++j) b[j] = 0.f;
  for (int i = s + g; i < e; i += 16) {
    int c = cn[i];
    uint4 v = *(const uint4*)&y1n[(size_t)c * 16 + 4 * f];
    float2 p0 = up16(v.x), p1 = up16(v.y), p2 = up16(v.z), p3 = up16(v.w);
    b[0] += p0.x; b[1] += p0.y; b[2] += p1.x; b[3] += p1.y;
    b[4] += p2.x; b[5] += p2.y; b[6] += p3.x; b[7] += p3.y;
  }
#pragma unroll
  for (int w = 4; w <= 32; w <<= 1) {
#pragma unroll
    for (int j = 0; j < 8; ++j) b[j] += __shfl_xor(b[j], w);
  }
  float invn = 1.f / (float)max(e - s, 1);

  size_t base = (size_t)node * 64;
  if (g == 0) {
    const float4 r0 = *(const float4*)(r1 + base + 8 * f);
    const float4 r1v = *(const float4*)(r1 + base + 8 * f + 4);
    float4 o0, o1;
    o0.x = fmaxf(a[0] * invp + r0.x, 0.f);
    o0.y = fmaxf(a[1] * invp + r0.y, 0.f);
    o0.z = fmaxf(a[2] * invp + r0.z, 0.f);
    o0.w = fmaxf(a[3] * invp + r0.w, 0.f);
    o1.x = fmaxf(a[4] * invp + r1v.x, 0.f);
    o1.y = fmaxf(a[5] * invp + r1v.y, 0.f);
    o1.z = fmaxf(a[6] * invp + r1v.z, 0.f);
    o1.w = fmaxf(a[7] * invp + r1v.w, 0.f);
    *(float4*)(z + base + 8 * f) = o0;
    *(float4*)(z + base + 8 * f + 4) = o1;
  } else if (g == 1) {
    const float4 r0 = *(const float4*)(r1 + base + 32 + 8 * f);
    const float4 r1v = *(const float4*)(r1 + base + 32 + 8 * f + 4);
    float4 o0, o1;
    o0.x = fmaxf(b[0] * invn + r0.x, 0.f);
    o0.y = fmaxf(b[1] * invn + r0.y, 0.f);
    o0.z = fmaxf(b[2] * invn + r0.z, 0.f);
    o0.w = fmaxf(b[3] * invn + r0.w, 0.f);
    o1.x = fmaxf(b[4] * invn + r1v.x, 0.f);
    o1.y = fmaxf(b[5] * invn + r1v.y, 0.f);
    o1.z = fmaxf(b[6] * invn + r1v.z, 0.f);
    o1.w = fmaxf(b[7] * invn + r1v.w, 0.f);
    *(float4*)(z + base + 32 + 8 * f) = o0;
    *(float4*)(z + base + 32 + 8 * f + 4) = o1;
  }
}

// ---------------- pre-transform layer 2 ----------------
__global__ void k_mid(const float* __restrict__ z,
                      const float* __restrict__ w2_pl, const float* __restrict__ w2_pr,
                      const float* __restrict__ b2_p,
                      const float* __restrict__ w2_nl, const float* __restrict__ w2_nr,
                      const float* __restrict__ b2_n,
                      uint* __restrict__ u_pos, uint* __restrict__ u_neg,
                      float* __restrict__ r2) {
  const int t = blockIdx.y;
  const float* mat;
  const float* bias = nullptr;
  int srcHalf;            // 0 = zp, 1 = zn
  switch (t) {
    case 0: mat = w2_pl;            srcHalf = 0; break;
    case 1: mat = w2_nl;            srcHalf = 1; break;
    case 2: mat = w2_pl + 32 * 32;  srcHalf = 1; break;
    case 3: mat = w2_nl + 32 * 32;  srcHalf = 0; break;
    case 4: mat = w2_pr; bias = b2_p; srcHalf = 0; break;
    default: mat = w2_nr; bias = b2_n; srcHalf = 1; break;
  }

  __shared__ float s_m[HH][HH];
  for (int i = threadIdx.x; i < HH * HH; i += 256) s_m[i >> 5][i & 31] = mat[i];
  __syncthreads();

  int node = blockIdx.x * 256 + threadIdx.x;
  if (node >= NN) return;

  float acc[HH];
#pragma unroll
  for (int j = 0; j < HH; ++j) acc[j] = bias ? bias[j] : 0.f;

  const float4* zrow = (const float4*)(z + (size_t)node * 64 + srcHalf * 32);
#pragma unroll 4
  for (int k4 = 0; k4 < HH / 4; ++k4) {
    float4 v = zrow[k4];
#pragma unroll
    for (int u = 0; u < 4; ++u) {
      int k = k4 * 4 + u;
      float vv = (&v.x)[u];
#pragma unroll
      for (int j = 0; j < HH; ++j) acc[j] += vv * s_m[k][j];
    }
  }

  if (t < 4) {
    uint* o = (t < 2 ? u_pos : u_neg) + (size_t)node * 32 + (t & 1) * 16;
#pragma unroll
    for (int j = 0; j < 16; ++j) o[j] = pk16(acc[2 * j], acc[2 * j + 1]);
  } else {
    float* o = r2 + (size_t)node * 64 + (t - 4) * 32;
#pragma unroll
    for (int j = 0; j < HH; ++j) o[j] = acc[j];
  }
}

// ---------------- aggregation 2 (8 edges/iter, uint4 per lane) ----------------
__global__ void k_aggr2(const uint* __restrict__ u_pos, const uint* __restrict__ u_neg,
                        const int* __restrict__ rp, const int* __restrict__ cp,
                        const int* __restrict__ rn, const int* __restrict__ cn,
                        const float* __restrict__ r2,
                        float* __restrict__ out) {
  int gid  = blockIdx.x * 256 + threadIdx.x;
  int node = gid >> 6;
  if (node >= NN) return;
  int lane = threadIdx.x & 63;
  int g = lane >> 3;      // edge slot 0..7
  int f = lane & 7;       // uint4 index in row

  int s = rp[node], e = rp[node + 1];
  float a[8];
#pragma unroll
  for (int j = 0; j < 8; ++j) a[j] = 0.f;
  for (int i = s + g; i < e; i += 8) {
    int c = cp[i];
    uint4 v = *(const uint4*)&u_pos[(size_t)c * 32 + 4 * f];
    float2 p0 = up16(v.x), p1 = up16(v.y), p2 = up16(v.z), p3 = up16(v.w);
    a[0] += p0.x; a[1] += p0.y; a[2] += p1.x; a[3] += p1.y;
    a[4] += p2.x; a[5] += p2.y; a[6] += p3.x; a[7] += p3.y;
  }
#pragma unroll
  for (int w = 8; w <= 32; w <<= 1) {
#pragma unroll
    for (int j = 0; j < 8; ++j) a[j] += __shfl_xor(a[j], w);
  }
  float invp = 1.f / (float)max(e - s, 1);

  s = rn[node]; e = rn[node + 1];
  float b[8];
#pragma unroll
  for (int j = 0; j < 8; ++j) b[j] = 0.f;
  for (int i = s + g; i < e; i += 8) {
    int c = cn[i];
    uint4 v = *(const uint4*)&u_neg[(size_t)c * 32 + 4 * f];
    float2 p0 = up16(v.x), p1 = up16(v.y), p2 = up16(v.z), p3 = up16(v.w);
    b[0] += p0.x; b[1] += p0.y; b[2] += p1.x; b[3] += p1.y;
    b[4] += p2.x; b[5] += p2.y; b[6] += p3.x; b[7] += p3.y;
  }
#pragma unroll
  for (int w = 8; w <= 32; w <<= 1) {
#pragma unroll
    for (int j = 0; j < 8; ++j) b[j] += __shfl_xor(b[j], w);
  }
  float invn = 1.f / (float)max(e - s, 1);

  if (g == 0) {
    size_t base = (size_t)node * 64 + 8 * f;
    const float4 r0 = *(const float4*)(r2 + base);
    const float4 r1v = *(const float4*)(r2 + base + 4);
    float4 o0, o1;
    o0.x = fmaxf(a[0] * invp + b[0] * invn + r0.x, 0.f);
    o0.y = fmaxf(a[1] * invp + b[1] * invn + r0.y, 0.f);
    o0.z = fmaxf(a[2] * invp + b[2] * invn + r0.z, 0.f);
    o0.w = fmaxf(a[3] * invp + b[3] * invn + r0.w, 0.f);
    o1.x = fmaxf(a[4] * invp + b[4] * invn + r1v.x, 0.f);
    o1.y = fmaxf(a[5] * invp + b[5] * invn + r1v.y, 0.f);
    o1.z = fmaxf(a[6] * invp + b[6] * invn + r1v.z, 0.f);
    o1.w = fmaxf(a[7] * invp + b[7] * invn + r1v.w, 0.f);
    *(float4*)(out + base) = o0;
    *(float4*)(out + base + 4) = o1;
  }
}

// ---------------- launch ----------------

extern "C" void kernel_launch(void* const* d_in, const int* in_sizes, int n_in,
                              void* d_out, int out_size, void* d_ws, size_t ws_size,
                              hipStream_t stream) {
  const float* x     = (const float*)d_in[0];
  const int*   pe    = (const int*)d_in[1];
  const int*   ne    = (const int*)d_in[2];
  const float* w1_pl = (const float*)d_in[3];
  const float* w1_pr = (const float*)d_in[4];
  const float* b1_p  = (const float*)d_in[5];
  const float* w1_nl = (const float*)d_in[6];
  const float* w1_nr = (const float*)d_in[7];
  const float* b1_n  = (const float*)d_in[8];
  const float* w2_pl = (const float*)d_in[9];
  const float* w2_pr = (const float*)d_in[10];
  const float* b2_p  = (const float*)d_in[11];
  const float* w2_nl = (const float*)d_in[12];
  const float* w2_nr = (const float*)d_in[13];
  const float* b2_n  = (const float*)d_in[14];

  char* ws = (char*)d_ws;
  size_t off = 0;
  auto alloc = [&](size_t bytes) -> char* {
    char* p = ws + off;
    off = (off + bytes + 255) & ~(size_t)255;
    return p;
  };

  int* row_p = (int*)alloc((size_t)(NN + 1) * 4);
  int* row_n = (int*)alloc((size_t)(NN + 1) * 4);
  int* col_p = (int*)alloc((size_t)NE * 4);
  int* col_n = (int*)alloc((size_t)NE * 4);
  int* tot   = (int*)alloc((size_t)2 * 512 * 4);
  int* base  = (int*)alloc((size_t)2 * 513 * 4);

  // union region A (25.6MB):
  //   CSR build phase: [partP 6.4MB][partN 6.4MB][part_hist 2MB][free]
  //   k_mid..k_aggr2:  [u_pos 12.8MB][u_neg 12.8MB]
  char* regA  = alloc((size_t)NN * 64 * 4);
  uint* partP = (uint*)regA;
  uint* partN = (uint*)(regA + (size_t)NE * 4);
  int*  part_hist = (int*)(regA + (size_t)2 * NE * 4);   // 2*HB*512*4 = 2MB
  uint* u_pos = (uint*)regA;
  uint* u_neg = (uint*)(regA + (size_t)NN * 32 * 4);

  // union region B (25.6MB): y1p+y1n (k_pre1..k_aggr1, 12.8MB) / r2 (k_mid..k_aggr2)
  char*  regB = alloc((size_t)NN * 64 * 4);
  uint*  y1p  = (uint*)regB;
  uint*  y1n  = (uint*)(regB + (size_t)NN * 16 * 4);
  float* r2   = (float*)regB;

  // r1 and z both live in d_out; k_aggr2 fully overwrites d_out at the end.
  float* r1 = (float*)d_out;
  float* z  = (float*)d_out;

  const int nb = NBLK;
  const int ab = (NN * 64 + 255) / 256;

  dim3 pg(nb, 2);
  k_pre1<<<pg, 256, 0, stream>>>(x, w1_pl, w1_pr, b1_p, w1_nl, w1_nr, b1_n,
                                 y1p, y1n, r1);

  dim3 hg(HB, 2);
  c_hist<<<hg, 256, 0, stream>>>(pe, ne, part_hist);
  dim3 cg(512, 2);
  c_colscan<<<cg, HB, 0, stream>>>(part_hist, tot);
  c_basescan<<<1, 1024, 0, stream>>>(tot, base);
  dim3 sg(SB, 2);
  c_scatter<<<sg, 512, 0, stream>>>(pe, ne, part_hist, base, partP, partN);
  c_bucket<<<2 * NBKT, 256, 0, stream>>>(partP, partN, base,
                                         row_p, row_n, col_p, col_n);

  k_aggr1<<<ab, 256, 0, stream>>>(y1p, y1n, row_p, col_p, row_n, col_n, r1, z);

  dim3 g2(nb, 6);
  k_mid<<<g2, 256, 0, stream>>>(z, w2_pl, w2_pr, b2_p, w2_nl, w2_nr, b2_n,
                                u_pos, u_neg, r2);

  k_aggr2<<<ab, 256, 0, stream>>>(u_pos, u_neg, row_p, col_p, row_n, col_n, r2,
                                  (float*)d_out);
}

// Round 11
// 299.752 us; speedup vs baseline: 1.1018x; 1.0469x over previous
//
#include <hip/hip_runtime.h>
#include <hip/hip_fp16.h>

using uint = unsigned int;

static constexpr int NN  = 100000;   // nodes
static constexpr int NE  = 1600000;  // edges per set
static constexpr int DIM = 64;
static constexpr int HH  = 32;
static constexpr int NBLK = (NN + 255) / 256;   // 391 node-blocks
static constexpr int HB   = 256;                // partition chunks per edge set (R7 value)
static constexpr int CHUNK = NE / HB;           // 6250 (exact)
static constexpr int BSH  = 9;                  // bucket = dst >> 9 (512 nodes/bucket)
static constexpr int BSZ  = 512;
static constexpr int NBKT = (NN + BSZ - 1) / BSZ;  // 196 live buckets (of 256 bins)

__device__ __forceinline__ float2 up16(uint v) {
  __half2 h = *reinterpret_cast<__half2*>(&v);
  return __half22float2(h);
}
__device__ __forceinline__ uint pk16(float a, float b) {
  __half2 h = __floats2half2_rn(a, b);
  return *reinterpret_cast<uint*>(&h);
}

// ================= atomic-free CSR build (radix partition by dst>>9) =================
// R7-proven shapes: 256 chunks x 256 bins; scatter runs ~24 edges (~96B) per (chunk,bin).

// A1: per-chunk 256-bin histogram. part_hist[set][chunk][bin]
__global__ void c_hist(const int* __restrict__ pe, const int* __restrict__ ne,
                       int* __restrict__ part_hist) {
  const int set = blockIdx.y;
  const int* dstA = (set ? ne : pe) + NE;
  __shared__ int h[256];
  h[threadIdx.x] = 0;
  __syncthreads();
  int lo = blockIdx.x * CHUNK;
  int hi = lo + CHUNK;
  for (int i = lo + threadIdx.x; i < hi; i += 256)
    atomicAdd(&h[dstA[i] >> BSH], 1);
  __syncthreads();
  part_hist[(size_t)(set * HB + blockIdx.x) * 256 + threadIdx.x] = h[threadIdx.x];
}

// A2: per (set,bin): exclusive scan over the HB chunk-partials (in place); total->tot.
__global__ void c_colscan(int* __restrict__ part_hist, int* __restrict__ tot) {
  const int set = blockIdx.y;
  const int k   = blockIdx.x;   // bin 0..255
  const int t   = threadIdx.x;  // chunk 0..255
  int v = part_hist[(size_t)(set * HB + t) * 256 + k];
  __shared__ int sm[256];
  sm[t] = v;
  __syncthreads();
  for (int off = 1; off < 256; off <<= 1) {
    int add = (t >= off) ? sm[t - off] : 0;
    __syncthreads();
    sm[t] += add;
    __syncthreads();
  }
  part_hist[(size_t)(set * HB + t) * 256 + k] = (t == 0) ? 0 : sm[t - 1];
  if (t == 255) tot[set * 256 + k] = sm[255];
}

// A3: one block, 512 threads: exclusive scan of 256 bins per set -> base[set][0..256]
__global__ void c_basescan(const int* __restrict__ tot, int* __restrict__ base) {
  const int t   = threadIdx.x;
  const int seg = t >> 8;      // set
  const int idx = t & 255;     // bin
  int v = tot[seg * 256 + idx];
  __shared__ int sm[512];
  sm[t] = v;
  __syncthreads();
  for (int off = 1; off < 256; off <<= 1) {
    int add = (idx >= off) ? sm[t - off] : 0;
    __syncthreads();
    sm[t] += add;
    __syncthreads();
  }
  base[seg * 257 + idx] = (idx == 0) ? 0 : sm[t - 1];
  if (idx == 255) base[seg * 257 + 256] = sm[t];   // == NE
}

// A4: scatter packed (src<<9 | dst&511) into bucket-partitioned order.
// LDS counters start at the chunk's reserved absolute offset per bin -> no global atomics.
__global__ void c_scatter(const int* __restrict__ pe, const int* __restrict__ ne,
                          const int* __restrict__ part_hist, const int* __restrict__ base,
                          uint* __restrict__ partP, uint* __restrict__ partN) {
  const int set = blockIdx.y;
  const int b   = blockIdx.x;
  const int* srcA = set ? ne : pe;
  const int* dstA = srcA + NE;
  uint* part = set ? partN : partP;
  __shared__ int off[256];
  const int* ph = part_hist + (size_t)(set * HB + b) * 256;
  off[threadIdx.x] = base[set * 257 + threadIdx.x] + ph[threadIdx.x];
  __syncthreads();
  int lo = b * CHUNK;
  int hi = lo + CHUNK;
  for (int i = lo + threadIdx.x; i < hi; i += 256) {
    int src = srcA[i];
    int dst = dstA[i];
    int pos = atomicAdd(&off[dst >> BSH], 1);
    part[pos] = ((uint)src << BSH) | (uint)(dst & (BSZ - 1));
  }
}

// B: per-bucket CSR (LDS count -> LDS scan -> rowptr + col scatter). Standalone,
// 512 threads, 6KB LDS.
__global__ void c_bucket(const uint* __restrict__ partP, const uint* __restrict__ partN,
                         const int* __restrict__ base,
                         int* __restrict__ row_p, int* __restrict__ row_n,
                         int* __restrict__ col_p, int* __restrict__ col_n) {
  const int bx = blockIdx.x;            // [0, 2*NBKT)
  const int t  = threadIdx.x;           // 0..511
  const int set = (bx >= NBKT) ? 1 : 0;
  const int k   = bx - (set ? NBKT : 0);
  const uint* part = set ? partN : partP;
  int* row = set ? row_n : row_p;
  int* col = set ? col_n : col_p;
  const int lo = k * BSZ;
  const int hi = min(lo + BSZ, NN);
  const int s = base[set * 257 + k];
  const int e = base[set * 257 + k + 1];

  __shared__ int cnt[BSZ], rowl[BSZ], cnt2[BSZ];
  cnt[t] = 0; cnt2[t] = 0;
  __syncthreads();
  for (int i = s + t; i < e; i += 512)
    atomicAdd(&cnt[part[i] & (BSZ - 1)], 1);
  __syncthreads();
  rowl[t] = cnt[t];
  __syncthreads();
  for (int off = 1; off < BSZ; off <<= 1) {
    int a0 = (t >= off) ? rowl[t - off] : 0;
    __syncthreads();
    rowl[t] += a0;
    __syncthreads();
  }
  if (lo + t < hi) row[lo + t] = s + (t ? rowl[t - 1] : 0);
  if (k == NBKT - 1 && t == 0) row[NN] = NE;
  for (int i = s + t; i < e; i += 512) {
    uint p = part[i];
    int l = p & (BSZ - 1);
    int pos = s + (l ? rowl[l - 1] : 0) + atomicAdd(&cnt2[l], 1);
    col[pos] = (int)(p >> BSH);
  }
}

// ---------------- layer-1 pre-transform (standalone; full occupancy) ----------------
// y1{p,n}[node] = x@wl (f16, 64B row); r1 = x@wr + b (f32, in d_out)
__global__ void k_pre1(const float* __restrict__ x,
                       const float* __restrict__ w1_pl, const float* __restrict__ w1_pr,
                       const float* __restrict__ b1_p,
                       const float* __restrict__ w1_nl, const float* __restrict__ w1_nr,
                       const float* __restrict__ b1_n,
                       uint* __restrict__ y1p, uint* __restrict__ y1n,
                       float* __restrict__ r1) {
  const int h = blockIdx.y;
  const float* wl   = h ? w1_nl : w1_pl;  // [64][32]
  const float* wr   = h ? w1_nr : w1_pr;  // [64][32]
  const float* bias = h ? b1_n  : b1_p;

  __shared__ float s_wl[DIM * HH];
  __shared__ float s_wr[DIM * HH];
  for (int i = threadIdx.x; i < DIM * HH; i += 256) {
    s_wl[i] = wl[i];
    s_wr[i] = wr[i];
  }
  __syncthreads();

  int node = blockIdx.x * 256 + threadIdx.x;
  if (node >= NN) return;

  float ay[HH], ar[HH];
#pragma unroll
  for (int j = 0; j < HH; ++j) { ay[j] = 0.f; ar[j] = bias[j]; }

  const float4* xrow = (const float4*)(x + (size_t)node * DIM);
#pragma unroll 4
  for (int k4 = 0; k4 < DIM / 4; ++k4) {
    float4 xv = xrow[k4];
#pragma unroll
    for (int u = 0; u < 4; ++u) {
      int k = k4 * 4 + u;
      float xk = (&xv.x)[u];
#pragma unroll
      for (int j = 0; j < HH; ++j) {
        ay[j] += xk * s_wl[k * HH + j];
        ar[j] += xk * s_wr[k * HH + j];
      }
    }
  }

  uint*  yo = (h ? y1n : y1p) + (size_t)node * 16;
  float* ro = r1 + (size_t)node * 64 + h * 32;
#pragma unroll
  for (int j = 0; j < 16; ++j) yo[j] = pk16(ay[2 * j], ay[2 * j + 1]);
#pragma unroll
  for (int j = 0; j < HH; ++j) ro[j] = ar[j];
}

// ---------------- aggregation 1 (16 edges/iter, uint4 per lane, split tables) --------
// NOTE: r1 and z ALIAS (both d_out): same-thread read-then-write only.
__global__ void k_aggr1(const uint* __restrict__ y1p, const uint* __restrict__ y1n,
                        const int* __restrict__ rp, const int* __restrict__ cp,
                        const int* __restrict__ rn, const int* __restrict__ cn,
                        const float* r1,
                        float* z) {
  int gid  = blockIdx.x * 256 + threadIdx.x;
  int node = gid >> 6;
  if (node >= NN) return;
  int lane = threadIdx.x & 63;
  int g = lane >> 2;      // edge slot 0..15
  int f = lane & 3;       // uint4 index

  int s = rp[node], e = rp[node + 1];
  float a[8];
#pragma unroll
  for (int j = 0; j < 8; ++j) a[j] = 0.f;
  for (int i = s + g; i < e; i += 16) {
    int c = cp[i];
    uint4 v = *(const uint4*)&y1p[(size_t)c * 16 + 4 * f];
    float2 p0 = up16(v.x), p1 = up16(v.y), p2 = up16(v.z), p3 = up16(v.w);
    a[0] += p0.x; a[1] += p0.y; a[2] += p1.x; a[3] += p1.y;
    a[4] += p2.x; a[5] += p2.y; a[6] += p3.x; a[7] += p3.y;
  }
#pragma unroll
  for (int w = 4; w <= 32; w <<= 1) {
#pragma unroll
    for (int j = 0; j < 8; ++j) a[j] += __shfl_xor(a[j], w);
  }
  float invp = 1.f / (float)max(e - s, 1);

  s = rn[node]; e = rn[node + 1];
  float b[8];
#pragma unroll
  for (int j = 0; j < 8; ++j) b[j] = 0.f;
  for (int i = s + g; i < e; i += 16) {
    int c = cn[i];
    uint4 v = *(const uint4*)&y1n[(size_t)c * 16 + 4 * f];
    float2 p0 = up16(v.x), p1 = up16(v.y), p2 = up16(v.z), p3 = up16(v.w);
    b[0] += p0.x; b[1] += p0.y; b[2] += p1.x; b[3] += p1.y;
    b[4] += p2.x; b[5] += p2.y; b[6] += p3.x; b[7] += p3.y;
  }
#pragma unroll
  for (int w = 4; w <= 32; w <<= 1) {
#pragma unroll
    for (int j = 0; j < 8; ++j) b[j] += __shfl_xor(b[j], w);
  }
  float invn = 1.f / (float)max(e - s, 1);

  size_t base = (size_t)node * 64;
  if (g == 0) {
    const float4 r0 = *(const float4*)(r1 + base + 8 * f);
    const float4 r1v = *(const float4*)(r1 + base + 8 * f + 4);
    float4 o0, o1;
    o0.x = fmaxf(a[0] * invp + r0.x, 0.f);
    o0.y = fmaxf(a[1] * invp + r0.y, 0.f);
    o0.z = fmaxf(a[2] * invp + r0.z, 0.f);
    o0.w = fmaxf(a[3] * invp + r0.w, 0.f);
    o1.x = fmaxf(a[4] * invp + r1v.x, 0.f);
    o1.y = fmaxf(a[5] * invp + r1v.y, 0.f);
    o1.z = fmaxf(a[6] * invp + r1v.z, 0.f);
    o1.w = fmaxf(a[7] * invp + r1v.w, 0.f);
    *(float4*)(z + base + 8 * f) = o0;
    *(float4*)(z + base + 8 * f + 4) = o1;
  } else if (g == 1) {
    const float4 r0 = *(const float4*)(r1 + base + 32 + 8 * f);
    const float4 r1v = *(const float4*)(r1 + base + 32 + 8 * f + 4);
    float4 o0, o1;
    o0.x = fmaxf(b[0] * invn + r0.x, 0.f);
    o0.y = fmaxf(b[1] * invn + r0.y, 0.f);
    o0.z = fmaxf(b[2] * invn + r0.z, 0.f);
    o0.w = fmaxf(b[3] * invn + r0.w, 0.f);
    o1.x = fmaxf(b[4] * invn + r1v.x, 0.f);
    o1.y = fmaxf(b[5] * invn + r1v.y, 0.f);
    o1.z = fmaxf(b[6] * invn + r1v.z, 0.f);
    o1.w = fmaxf(b[7] * invn + r1v.w, 0.f);
    *(float4*)(z + base + 32 + 8 * f) = o0;
    *(float4*)(z + base + 32 + 8 * f + 4) = o1;
  }
}

// ---------------- pre-transform layer 2 ----------------
__global__ void k_mid(const float* __restrict__ z,
                      const float* __restrict__ w2_pl, const float* __restrict__ w2_pr,
                      const float* __restrict__ b2_p,
                      const float* __restrict__ w2_nl, const float* __restrict__ w2_nr,
                      const float* __restrict__ b2_n,
                      uint* __restrict__ u_pos, uint* __restrict__ u_neg,
                      float* __restrict__ r2) {
  const int t = blockIdx.y;
  const float* mat;
  const float* bias = nullptr;
  int srcHalf;            // 0 = zp, 1 = zn
  switch (t) {
    case 0: mat = w2_pl;            srcHalf = 0; break;
    case 1: mat = w2_nl;            srcHalf = 1; break;
    case 2: mat = w2_pl + 32 * 32;  srcHalf = 1; break;
    case 3: mat = w2_nl + 32 * 32;  srcHalf = 0; break;
    case 4: mat = w2_pr; bias = b2_p; srcHalf = 0; break;
    default: mat = w2_nr; bias = b2_n; srcHalf = 1; break;
  }

  __shared__ float s_m[HH][HH];
  for (int i = threadIdx.x; i < HH * HH; i += 256) s_m[i >> 5][i & 31] = mat[i];
  __syncthreads();

  int node = blockIdx.x * 256 + threadIdx.x;
  if (node >= NN) return;

  float acc[HH];
#pragma unroll
  for (int j = 0; j < HH; ++j) acc[j] = bias ? bias[j] : 0.f;

  const float4* zrow = (const float4*)(z + (size_t)node * 64 + srcHalf * 32);
#pragma unroll 4
  for (int k4 = 0; k4 < HH / 4; ++k4) {
    float4 v = zrow[k4];
#pragma unroll
    for (int u = 0; u < 4; ++u) {
      int k = k4 * 4 + u;
      float vv = (&v.x)[u];
#pragma unroll
      for (int j = 0; j < HH; ++j) acc[j] += vv * s_m[k][j];
    }
  }

  if (t < 4) {
    uint* o = (t < 2 ? u_pos : u_neg) + (size_t)node * 32 + (t & 1) * 16;
#pragma unroll
    for (int j = 0; j < 16; ++j) o[j] = pk16(acc[2 * j], acc[2 * j + 1]);
  } else {
    float* o = r2 + (size_t)node * 64 + (t - 4) * 32;
#pragma unroll
    for (int j = 0; j < HH; ++j) o[j] = acc[j];
  }
}

// ---------------- aggregation 2 (8 edges/iter, uint4 per lane) ----------------
__global__ void k_aggr2(const uint* __restrict__ u_pos, const uint* __restrict__ u_neg,
                        const int* __restrict__ rp, const int* __restrict__ cp,
                        const int* __restrict__ rn, const int* __restrict__ cn,
                        const float* __restrict__ r2,
                        float* __restrict__ out) {
  int gid  = blockIdx.x * 256 + threadIdx.x;
  int node = gid >> 6;
  if (node >= NN) return;
  int lane = threadIdx.x & 63;
  int g = lane >> 3;      // edge slot 0..7
  int f = lane & 7;       // uint4 index in row

  int s = rp[node], e = rp[node + 1];
  float a[8];
#pragma unroll
  for (int j = 0; j < 8; ++j) a[j] = 0.f;
  for (int i = s + g; i < e; i += 8) {
    int c = cp[i];
    uint4 v = *(const uint4*)&u_pos[(size_t)c * 32 + 4 * f];
    float2 p0 = up16(v.x), p1 = up16(v.y), p2 = up16(v.z), p3 = up16(v.w);
    a[0] += p0.x; a[1] += p0.y; a[2] += p1.x; a[3] += p1.y;
    a[4] += p2.x; a[5] += p2.y; a[6] += p3.x; a[7] += p3.y;
  }
#pragma unroll
  for (int w = 8; w <= 32; w <<= 1) {
#pragma unroll
    for (int j = 0; j < 8; ++j) a[j] += __shfl_xor(a[j], w);
  }
  float invp = 1.f / (float)max(e - s, 1);

  s = rn[node]; e = rn[node + 1];
  float b[8];
#pragma unroll
  for (int j = 0; j < 8; ++j) b[j] = 0.f;
  for (int i = s + g; i < e; i += 8) {
    int c = cn[i];
    uint4 v = *(const uint4*)&u_neg[(size_t)c * 32 + 4 * f];
    float2 p0 = up16(v.x), p1 = up16(v.y), p2 = up16(v.z), p3 = up16(v.w);
    b[0] += p0.x; b[1] += p0.y; b[2] += p1.x; b[3] += p1.y;
    b[4] += p2.x; b[5] += p2.y; b[6] += p3.x; b[7] += p3.y;
  }
#pragma unroll
  for (int w = 8; w <= 32; w <<= 1) {
#pragma unroll
    for (int j = 0; j < 8; ++j) b[j] += __shfl_xor(b[j], w);
  }
  float invn = 1.f / (float)max(e - s, 1);

  if (g == 0) {
    size_t base = (size_t)node * 64 + 8 * f;
    const float4 r0 = *(const float4*)(r2 + base);
    const float4 r1v = *(const float4*)(r2 + base + 4);
    float4 o0, o1;
    o0.x = fmaxf(a[0] * invp + b[0] * invn + r0.x, 0.f);
    o0.y = fmaxf(a[1] * invp + b[1] * invn + r0.y, 0.f);
    o0.z = fmaxf(a[2] * invp + b[2] * invn + r0.z, 0.f);
    o0.w = fmaxf(a[3] * invp + b[3] * invn + r0.w, 0.f);
    o1.x = fmaxf(a[4] * invp + b[4] * invn + r1v.x, 0.f);
    o1.y = fmaxf(a[5] * invp + b[5] * invn + r1v.y, 0.f);
    o1.z = fmaxf(a[6] * invp + b[6] * invn + r1v.z, 0.f);
    o1.w = fmaxf(a[7] * invp + b[7] * invn + r1v.w, 0.f);
    *(float4*)(out + base) = o0;
    *(float4*)(out + base + 4) = o1;
  }
}

// ---------------- launch ----------------

extern "C" void kernel_launch(void* const* d_in, const int* in_sizes, int n_in,
                              void* d_out, int out_size, void* d_ws, size_t ws_size,
                              hipStream_t stream) {
  const float* x     = (const float*)d_in[0];
  const int*   pe    = (const int*)d_in[1];
  const int*   ne    = (const int*)d_in[2];
  const float* w1_pl = (const float*)d_in[3];
  const float* w1_pr = (const float*)d_in[4];
  const float* b1_p  = (const float*)d_in[5];
  const float* w1_nl = (const float*)d_in[6];
  const float* w1_nr = (const float*)d_in[7];
  const float* b1_n  = (const float*)d_in[8];
  const float* w2_pl = (const float*)d_in[9];
  const float* w2_pr = (const float*)d_in[10];
  const float* b2_p  = (const float*)d_in[11];
  const float* w2_nl = (const float*)d_in[12];
  const float* w2_nr = (const float*)d_in[13];
  const float* b2_n  = (const float*)d_in[14];

  char* ws = (char*)d_ws;
  size_t off = 0;
  auto alloc = [&](size_t bytes) -> char* {
    char* p = ws + off;
    off = (off + bytes + 255) & ~(size_t)255;
    return p;
  };

  int* row_p = (int*)alloc((size_t)(NN + 1) * 4);
  int* row_n = (int*)alloc((size_t)(NN + 1) * 4);
  int* col_p = (int*)alloc((size_t)NE * 4);
  int* col_n = (int*)alloc((size_t)NE * 4);
  int* tot   = (int*)alloc((size_t)2 * 256 * 4);
  int* base  = (int*)alloc((size_t)2 * 257 * 4);

  // union region A (25.6MB):
  //   CSR build phase: [partP 6.4MB][partN 6.4MB][part_hist 512KB][free]
  //   k_mid..k_aggr2:  [u_pos 12.8MB][u_neg 12.8MB]
  char* regA  = alloc((size_t)NN * 64 * 4);
  uint* partP = (uint*)regA;
  uint* partN = (uint*)(regA + (size_t)NE * 4);
  int*  part_hist = (int*)(regA + (size_t)2 * NE * 4);   // 2*HB*256*4 = 512KB
  uint* u_pos = (uint*)regA;
  uint* u_neg = (uint*)(regA + (size_t)NN * 32 * 4);

  // union region B (25.6MB): y1p+y1n (k_pre1..k_aggr1, 12.8MB) / r2 (k_mid..k_aggr2)
  char*  regB = alloc((size_t)NN * 64 * 4);
  uint*  y1p  = (uint*)regB;
  uint*  y1n  = (uint*)(regB + (size_t)NN * 16 * 4);
  float* r2   = (float*)regB;

  // r1 and z both live in d_out; k_aggr2 fully overwrites d_out at the end.
  float* r1 = (float*)d_out;
  float* z  = (float*)d_out;

  const int nb = NBLK;
  const int ab = (NN * 64 + 255) / 256;

  dim3 pg(nb, 2);
  k_pre1<<<pg, 256, 0, stream>>>(x, w1_pl, w1_pr, b1_p, w1_nl, w1_nr, b1_n,
                                 y1p, y1n, r1);

  dim3 hg(HB, 2);
  c_hist<<<hg, 256, 0, stream>>>(pe, ne, part_hist);
  dim3 cg(256, 2);
  c_colscan<<<cg, 256, 0, stream>>>(part_hist, tot);
  c_basescan<<<1, 512, 0, stream>>>(tot, base);
  c_scatter<<<hg, 256, 0, stream>>>(pe, ne, part_hist, base, partP, partN);
  c_bucket<<<2 * NBKT, 512, 0, stream>>>(partP, partN, base,
                                         row_p, row_n, col_p, col_n);

  k_aggr1<<<ab, 256, 0, stream>>>(y1p, y1n, row_p, col_p, row_n, col_n, r1, z);

  dim3 g2(nb, 6);
  k_mid<<<g2, 256, 0, stream>>>(z, w2_pl, w2_pr, b2_p, w2_nl, w2_nr, b2_n,
                                u_pos, u_neg, r2);

  k_aggr2<<<ab, 256, 0, stream>>>(u_pos, u_neg, row_p, col_p, row_n, col_n, r2,
                                  (float*)d_out);
}

// Round 12
// 297.103 us; speedup vs baseline: 1.1117x; 1.0089x over previous
//
#include <hip/hip_runtime.h>
#include <hip/hip_fp16.h>

using uint = unsigned int;

static constexpr int NN  = 100000;   // nodes
static constexpr int NE  = 1600000;  // edges per set
static constexpr int DIM = 64;
static constexpr int HH  = 32;
static constexpr int NBLK = (NN + 511) / 512;   // 196 pre1 node-blocks (512 nodes each)
static constexpr int HB   = 256;                // partition chunks per edge set
static constexpr int CHUNK = NE / HB;           // 6250 (exact)
static constexpr int BSH  = 9;                  // bucket = dst >> 9 (512 nodes/bucket)
static constexpr int BSZ  = 512;
static constexpr int NBKT = (NN + BSZ - 1) / BSZ;  // 196 live buckets (of 256 bins)

__device__ __forceinline__ float2 up16(uint v) {
  __half2 h = *reinterpret_cast<__half2*>(&v);
  return __half22float2(h);
}
__device__ __forceinline__ uint pk16(float a, float b) {
  __half2 h = __floats2half2_rn(a, b);
  return *reinterpret_cast<uint*>(&h);
}

// ================= atomic-free CSR build (radix partition by dst>>9) =================
// R6-proven shapes: 256 chunks x 256 bins; scatter runs ~32 edges (~128B) per (chunk,bin).

// A1: per-chunk 256-bin histogram. part_hist[set][chunk][bin]
__global__ void c_hist(const int* __restrict__ pe, const int* __restrict__ ne,
                       int* __restrict__ part_hist) {
  const int set = blockIdx.y;
  const int* dstA = (set ? ne : pe) + NE;
  __shared__ int h[256];
  h[threadIdx.x] = 0;
  __syncthreads();
  int lo = blockIdx.x * CHUNK;
  int hi = lo + CHUNK;
  for (int i = lo + threadIdx.x; i < hi; i += 256)
    atomicAdd(&h[dstA[i] >> BSH], 1);
  __syncthreads();
  part_hist[(size_t)(set * HB + blockIdx.x) * 256 + threadIdx.x] = h[threadIdx.x];
}

// A2: per (set,bin): exclusive scan over the HB chunk-partials (in place); total->tot.
__global__ void c_colscan(int* __restrict__ part_hist, int* __restrict__ tot) {
  const int set = blockIdx.y;
  const int k   = blockIdx.x;   // bin 0..255
  const int t   = threadIdx.x;  // chunk 0..255
  int v = part_hist[(size_t)(set * HB + t) * 256 + k];
  __shared__ int sm[256];
  sm[t] = v;
  __syncthreads();
  for (int off = 1; off < 256; off <<= 1) {
    int add = (t >= off) ? sm[t - off] : 0;
    __syncthreads();
    sm[t] += add;
    __syncthreads();
  }
  part_hist[(size_t)(set * HB + t) * 256 + k] = (t == 0) ? 0 : sm[t - 1];
  if (t == 255) tot[set * 256 + k] = sm[255];
}

// A3: one block, 512 threads: exclusive scan of 256 bins per set -> base[set][0..256]
__global__ void c_basescan(const int* __restrict__ tot, int* __restrict__ base) {
  const int t   = threadIdx.x;
  const int seg = t >> 8;      // set
  const int idx = t & 255;     // bin
  int v = tot[seg * 256 + idx];
  __shared__ int sm[512];
  sm[t] = v;
  __syncthreads();
  for (int off = 1; off < 256; off <<= 1) {
    int add = (idx >= off) ? sm[t - off] : 0;
    __syncthreads();
    sm[t] += add;
    __syncthreads();
  }
  base[seg * 257 + idx] = (idx == 0) ? 0 : sm[t - 1];
  if (idx == 255) base[seg * 257 + 256] = sm[t];   // == NE
}

// A4: scatter packed (src<<9 | dst&511) into bucket-partitioned order.
// LDS counters start at the chunk's reserved absolute offset per bin -> no global atomics.
__global__ void c_scatter(const int* __restrict__ pe, const int* __restrict__ ne,
                          const int* __restrict__ part_hist, const int* __restrict__ base,
                          uint* __restrict__ partP, uint* __restrict__ partN) {
  const int set = blockIdx.y;
  const int b   = blockIdx.x;
  const int* srcA = set ? ne : pe;
  const int* dstA = srcA + NE;
  uint* part = set ? partN : partP;
  __shared__ int off[256];
  const int* ph = part_hist + (size_t)(set * HB + b) * 256;
  off[threadIdx.x] = base[set * 257 + threadIdx.x] + ph[threadIdx.x];
  __syncthreads();
  int lo = b * CHUNK;
  int hi = lo + CHUNK;
  for (int i = lo + threadIdx.x; i < hi; i += 256) {
    int src = srcA[i];
    int dst = dstA[i];
    int pos = atomicAdd(&off[dst >> BSH], 1);
    part[pos] = ((uint)src << BSH) | (uint)(dst & (BSZ - 1));
  }
}

// B (+pre1 fused, 512 threads, LDS UNIONED at 16KB):
// Blocks [0, 2*NBKT): per-bucket CSR (count -> scan -> rowptr + col scatter).
// Blocks [2*NBKT, 2*NBKT+2*NBLK): layer-1 pre-transform, 512 nodes per block.
__global__ void c_bucket(const uint* __restrict__ partP, const uint* __restrict__ partN,
                         const int* __restrict__ base,
                         int* __restrict__ row_p, int* __restrict__ row_n,
                         int* __restrict__ col_p, int* __restrict__ col_n,
                         const float* __restrict__ x,
                         const float* __restrict__ w1_pl, const float* __restrict__ w1_pr,
                         const float* __restrict__ b1_p,
                         const float* __restrict__ w1_nl, const float* __restrict__ w1_nr,
                         const float* __restrict__ b1_n,
                         uint* __restrict__ y1u, float* __restrict__ r1) {
  __shared__ uint smem[4096];   // 16KB union: bucket uses 6KB, pre1 uses 16KB
  const int bx = blockIdx.x;
  const int t  = threadIdx.x;   // 0..511

  if (bx < 2 * NBKT) {
    // ---- bucket-CSR path (512 threads: 16 trips over ~8200 edges) ----
    const int set = (bx >= NBKT) ? 1 : 0;
    const int k   = bx - (set ? NBKT : 0);
    const uint* part = set ? partN : partP;
    int* row = set ? row_n : row_p;
    int* col = set ? col_n : col_p;
    const int lo = k * BSZ;
    const int hi = min(lo + BSZ, NN);
    const int s = base[set * 257 + k];
    const int e = base[set * 257 + k + 1];

    int* cnt  = (int*)smem;          // [512]
    int* rowl = (int*)smem + 512;    // [512]
    int* cnt2 = (int*)smem + 1024;   // [512]
    cnt[t] = 0; cnt2[t] = 0;
    __syncthreads();
    for (int i = s + t; i < e; i += 512)
      atomicAdd(&cnt[part[i] & (BSZ - 1)], 1);
    __syncthreads();
    rowl[t] = cnt[t];
    __syncthreads();
    for (int off = 1; off < BSZ; off <<= 1) {
      int a0 = (t >= off) ? rowl[t - off] : 0;
      __syncthreads();
      rowl[t] += a0;
      __syncthreads();
    }
    if (lo + t < hi) row[lo + t] = s + (t ? rowl[t - 1] : 0);
    if (k == NBKT - 1 && t == 0) row[NN] = NE;
    for (int i = s + t; i < e; i += 512) {
      uint p = part[i];
      int l = p & (BSZ - 1);
      int pos = s + (l ? rowl[l - 1] : 0) + atomicAdd(&cnt2[l], 1);
      col[pos] = (int)(p >> BSH);
    }
    return;
  }

  // ---- pre1 path: y1 = x@wl (f16, unified 128B rows); r1 = x@wr + b (f32, in d_out) ----
  const int pb   = bx - 2 * NBKT;
  const int h    = (pb >= NBLK) ? 1 : 0;
  const int nblk = pb - (h ? NBLK : 0);
  const float* wl   = h ? w1_nl : w1_pl;  // [64][32]
  const float* wr   = h ? w1_nr : w1_pr;  // [64][32]
  const float* bias = h ? b1_n  : b1_p;

  float* s_wl = (float*)smem;           // [64*32]
  float* s_wr = (float*)smem + 2048;    // [64*32]
  for (int i = t; i < DIM * HH; i += 512) {
    s_wl[i] = wl[i];
    s_wr[i] = wr[i];
  }
  __syncthreads();

  int node = nblk * 512 + t;
  if (node >= NN) return;

  float ay[HH], ar[HH];
#pragma unroll
  for (int j = 0; j < HH; ++j) { ay[j] = 0.f; ar[j] = bias[j]; }

  const float4* xrow = (const float4*)(x + (size_t)node * DIM);
#pragma unroll 4
  for (int k4 = 0; k4 < DIM / 4; ++k4) {
    float4 xv = xrow[k4];
#pragma unroll
    for (int u = 0; u < 4; ++u) {
      int k = k4 * 4 + u;
      float xk = (&xv.x)[u];
#pragma unroll
      for (int j = 0; j < HH; ++j) {
        ay[j] += xk * s_wl[k * HH + j];
        ar[j] += xk * s_wr[k * HH + j];
      }
    }
  }

  uint*  yo = y1u + (size_t)node * 32 + h * 16;
  float* ro = r1  + (size_t)node * 64 + h * 32;
#pragma unroll
  for (int j = 0; j < 16; ++j) yo[j] = pk16(ay[2 * j], ay[2 * j + 1]);
#pragma unroll
  for (int j = 0; j < HH; ++j) ro[j] = ar[j];
}

// ---------------- aggregation 1 (16 edges/iter, uint4 per lane) ----------------
// y1 row = 32 uints: [pos 0..15 | neg 16..31]. lane = (g,f): g=lane>>2 (16 edge
// slots), f=lane&3. Lane loads uint4 = features 8f..8f+7 of its half.
// NOTE: r1 and z ALIAS (both d_out): same-thread read-then-write only.
__global__ void k_aggr1(const uint* __restrict__ y1u,
                        const int* __restrict__ rp, const int* __restrict__ cp,
                        const int* __restrict__ rn, const int* __restrict__ cn,
                        const float* r1,
                        float* z) {
  int gid  = blockIdx.x * 256 + threadIdx.x;
  int node = gid >> 6;
  if (node >= NN) return;
  int lane = threadIdx.x & 63;
  int g = lane >> 2;      // edge slot 0..15
  int f = lane & 3;       // uint4 index within a 16-uint half

  int s = rp[node], e = rp[node + 1];
  float a[8];
#pragma unroll
  for (int j = 0; j < 8; ++j) a[j] = 0.f;
  for (int i = s + g; i < e; i += 16) {
    int c = cp[i];
    uint4 v = *(const uint4*)&y1u[(size_t)c * 32 + 4 * f];
    float2 p0 = up16(v.x), p1 = up16(v.y), p2 = up16(v.z), p3 = up16(v.w);
    a[0] += p0.x; a[1] += p0.y; a[2] += p1.x; a[3] += p1.y;
    a[4] += p2.x; a[5] += p2.y; a[6] += p3.x; a[7] += p3.y;
  }
#pragma unroll
  for (int w = 4; w <= 32; w <<= 1) {
#pragma unroll
    for (int j = 0; j < 8; ++j) a[j] += __shfl_xor(a[j], w);
  }
  float invp = 1.f / (float)max(e - s, 1);

  s = rn[node]; e = rn[node + 1];
  float b[8];
#pragma unroll
  for (int j = 0; j < 8; ++j) b[j] = 0.f;
  for (int i = s + g; i < e; i += 16) {
    int c = cn[i];
    uint4 v = *(const uint4*)&y1u[(size_t)c * 32 + 16 + 4 * f];
    float2 p0 = up16(v.x), p1 = up16(v.y), p2 = up16(v.z), p3 = up16(v.w);
    b[0] += p0.x; b[1] += p0.y; b[2] += p1.x; b[3] += p1.y;
    b[4] += p2.x; b[5] += p2.y; b[6] += p3.x; b[7] += p3.y;
  }
#pragma unroll
  for (int w = 4; w <= 32; w <<= 1) {
#pragma unroll
    for (int j = 0; j < 8; ++j) b[j] += __shfl_xor(b[j], w);
  }
  float invn = 1.f / (float)max(e - s, 1);

  size_t base = (size_t)node * 64;
  if (g == 0) {
    const float4 r0 = *(const float4*)(r1 + base + 8 * f);
    const float4 r1v = *(const float4*)(r1 + base + 8 * f + 4);
    float4 o0, o1;
    o0.x = fmaxf(a[0] * invp + r0.x, 0.f);
    o0.y = fmaxf(a[1] * invp + r0.y, 0.f);
    o0.z = fmaxf(a[2] * invp + r0.z, 0.f);
    o0.w = fmaxf(a[3] * invp + r0.w, 0.f);
    o1.x = fmaxf(a[4] * invp + r1v.x, 0.f);
    o1.y = fmaxf(a[5] * invp + r1v.y, 0.f);
    o1.z = fmaxf(a[6] * invp + r1v.z, 0.f);
    o1.w = fmaxf(a[7] * invp + r1v.w, 0.f);
    *(float4*)(z + base + 8 * f) = o0;
    *(float4*)(z + base + 8 * f + 4) = o1;
  } else if (g == 1) {
    const float4 r0 = *(const float4*)(r1 + base + 32 + 8 * f);
    const float4 r1v = *(const float4*)(r1 + base + 32 + 8 * f + 4);
    float4 o0, o1;
    o0.x = fmaxf(b[0] * invn + r0.x, 0.f);
    o0.y = fmaxf(b[1] * invn + r0.y, 0.f);
    o0.z = fmaxf(b[2] * invn + r0.z, 0.f);
    o0.w = fmaxf(b[3] * invn + r0.w, 0.f);
    o1.x = fmaxf(b[4] * invn + r1v.x, 0.f);
    o1.y = fmaxf(b[5] * invn + r1v.y, 0.f);
    o1.z = fmaxf(b[6] * invn + r1v.z, 0.f);
    o1.w = fmaxf(b[7] * invn + r1v.w, 0.f);
    *(float4*)(z + base + 32 + 8 * f) = o0;
    *(float4*)(z + base + 32 + 8 * f + 4) = o1;
  }
}

// ---------------- pre-transform layer 2 ----------------
__global__ void k_mid(const float* __restrict__ z,
                      const float* __restrict__ w2_pl, const float* __restrict__ w2_pr,
                      const float* __restrict__ b2_p,
                      const float* __restrict__ w2_nl, const float* __restrict__ w2_nr,
                      const float* __restrict__ b2_n,
                      uint* __restrict__ u_pos, uint* __restrict__ u_neg,
                      float* __restrict__ r2) {
  const int t = blockIdx.y;
  const float* mat;
  const float* bias = nullptr;
  int srcHalf;            // 0 = zp, 1 = zn
  switch (t) {
    case 0: mat = w2_pl;            srcHalf = 0; break;
    case 1: mat = w2_nl;            srcHalf = 1; break;
    case 2: mat = w2_pl + 32 * 32;  srcHalf = 1; break;
    case 3: mat = w2_nl + 32 * 32;  srcHalf = 0; break;
    case 4: mat = w2_pr; bias = b2_p; srcHalf = 0; break;
    default: mat = w2_nr; bias = b2_n; srcHalf = 1; break;
  }

  __shared__ float s_m[HH][HH];
  for (int i = threadIdx.x; i < HH * HH; i += 256) s_m[i >> 5][i & 31] = mat[i];
  __syncthreads();

  int node = blockIdx.x * 256 + threadIdx.x;
  if (node >= NN) return;

  float acc[HH];
#pragma unroll
  for (int j = 0; j < HH; ++j) acc[j] = bias ? bias[j] : 0.f;

  const float4* zrow = (const float4*)(z + (size_t)node * 64 + srcHalf * 32);
#pragma unroll 4
  for (int k4 = 0; k4 < HH / 4; ++k4) {
    float4 v = zrow[k4];
#pragma unroll
    for (int u = 0; u < 4; ++u) {
      int k = k4 * 4 + u;
      float vv = (&v.x)[u];
#pragma unroll
      for (int j = 0; j < HH; ++j) acc[j] += vv * s_m[k][j];
    }
  }

  if (t < 4) {
    uint* o = (t < 2 ? u_pos : u_neg) + (size_t)node * 32 + (t & 1) * 16;
#pragma unroll
    for (int j = 0; j < 16; ++j) o[j] = pk16(acc[2 * j], acc[2 * j + 1]);
  } else {
    float* o = r2 + (size_t)node * 64 + (t - 4) * 32;
#pragma unroll
    for (int j = 0; j < HH; ++j) o[j] = acc[j];
  }
}

// ---------------- aggregation 2 (8 edges/iter, uint4 per lane) ----------------
__global__ void k_aggr2(const uint* __restrict__ u_pos, const uint* __restrict__ u_neg,
                        const int* __restrict__ rp, const int* __restrict__ cp,
                        const int* __restrict__ rn, const int* __restrict__ cn,
                        const float* __restrict__ r2,
                        float* __restrict__ out) {
  int gid  = blockIdx.x * 256 + threadIdx.x;
  int node = gid >> 6;
  if (node >= NN) return;
  int lane = threadIdx.x & 63;
  int g = lane >> 3;      // edge slot 0..7
  int f = lane & 7;       // uint4 index in row

  int s = rp[node], e = rp[node + 1];
  float a[8];
#pragma unroll
  for (int j = 0; j < 8; ++j) a[j] = 0.f;
  for (int i = s + g; i < e; i += 8) {
    int c = cp[i];
    uint4 v = *(const uint4*)&u_pos[(size_t)c * 32 + 4 * f];
    float2 p0 = up16(v.x), p1 = up16(v.y), p2 = up16(v.z), p3 = up16(v.w);
    a[0] += p0.x; a[1] += p0.y; a[2] += p1.x; a[3] += p1.y;
    a[4] += p2.x; a[5] += p2.y; a[6] += p3.x; a[7] += p3.y;
  }
#pragma unroll
  for (int w = 8; w <= 32; w <<= 1) {
#pragma unroll
    for (int j = 0; j < 8; ++j) a[j] += __shfl_xor(a[j], w);
  }
  float invp = 1.f / (float)max(e - s, 1);

  s = rn[node]; e = rn[node + 1];
  float b[8];
#pragma unroll
  for (int j = 0; j < 8; ++j) b[j] = 0.f;
  for (int i = s + g; i < e; i += 8) {
    int c = cn[i];
    uint4 v = *(const uint4*)&u_neg[(size_t)c * 32 + 4 * f];
    float2 p0 = up16(v.x), p1 = up16(v.y), p2 = up16(v.z), p3 = up16(v.w);
    b[0] += p0.x; b[1] += p0.y; b[2] += p1.x; b[3] += p1.y;
    b[4] += p2.x; b[5] += p2.y; b[6] += p3.x; b[7] += p3.y;
  }
#pragma unroll
  for (int w = 8; w <= 32; w <<= 1) {
#pragma unroll
    for (int j = 0; j < 8; ++j) b[j] += __shfl_xor(b[j], w);
  }
  float invn = 1.f / (float)max(e - s, 1);

  if (g == 0) {
    size_t base = (size_t)node * 64 + 8 * f;
    const float4 r0 = *(const float4*)(r2 + base);
    const float4 r1v = *(const float4*)(r2 + base + 4);
    float4 o0, o1;
    o0.x = fmaxf(a[0] * invp + b[0] * invn + r0.x, 0.f);
    o0.y = fmaxf(a[1] * invp + b[1] * invn + r0.y, 0.f);
    o0.z = fmaxf(a[2] * invp + b[2] * invn + r0.z, 0.f);
    o0.w = fmaxf(a[3] * invp + b[3] * invn + r0.w, 0.f);
    o1.x = fmaxf(a[4] * invp + b[4] * invn + r1v.x, 0.f);
    o1.y = fmaxf(a[5] * invp + b[5] * invn + r1v.y, 0.f);
    o1.z = fmaxf(a[6] * invp + b[6] * invn + r1v.z, 0.f);
    o1.w = fmaxf(a[7] * invp + b[7] * invn + r1v.w, 0.f);
    *(float4*)(out + base) = o0;
    *(float4*)(out + base + 4) = o1;
  }
}

// ---------------- launch ----------------

extern "C" void kernel_launch(void* const* d_in, const int* in_sizes, int n_in,
                              void* d_out, int out_size, void* d_ws, size_t ws_size,
                              hipStream_t stream) {
  const float* x     = (const float*)d_in[0];
  const int*   pe    = (const int*)d_in[1];
  const int*   ne    = (const int*)d_in[2];
  const float* w1_pl = (const float*)d_in[3];
  const float* w1_pr = (const float*)d_in[4];
  const float* b1_p  = (const float*)d_in[5];
  const float* w1_nl = (const float*)d_in[6];
  const float* w1_nr = (const float*)d_in[7];
  const float* b1_n  = (const float*)d_in[8];
  const float* w2_pl = (const float*)d_in[9];
  const float* w2_pr = (const float*)d_in[10];
  const float* b2_p  = (const float*)d_in[11];
  const float* w2_nl = (const float*)d_in[12];
  const float* w2_nr = (const float*)d_in[13];
  const float* b2_n  = (const float*)d_in[14];

  char* ws = (char*)d_ws;
  size_t off = 0;
  auto alloc = [&](size_t bytes) -> char* {
    char* p = ws + off;
    off = (off + bytes + 255) & ~(size_t)255;
    return p;
  };

  int* row_p = (int*)alloc((size_t)(NN + 1) * 4);
  int* row_n = (int*)alloc((size_t)(NN + 1) * 4);
  int* col_p = (int*)alloc((size_t)NE * 4);
  int* col_n = (int*)alloc((size_t)NE * 4);
  int* part_hist = (int*)alloc((size_t)2 * HB * 256 * 4);  // 512KB
  int* tot   = (int*)alloc((size_t)2 * 256 * 4);
  int* base  = (int*)alloc((size_t)2 * 257 * 4);

  // union region A (25.6MB): packed partition arrays (c_scatter..c_bucket, 12.8MB)
  //                        / u_pos+u_neg (k_mid..k_aggr2, 25.6MB)
  char* regA  = alloc((size_t)NN * 64 * 4);
  uint* partP = (uint*)regA;
  uint* partN = (uint*)(regA + (size_t)NE * 4);
  uint* u_pos = (uint*)regA;
  uint* u_neg = (uint*)(regA + (size_t)NN * 32 * 4);

  // union region B (25.6MB): y1 (c_bucket..k_aggr1, 12.8MB) / r2 (k_mid..k_aggr2)
  char*  regB = alloc((size_t)NN * 64 * 4);
  uint*  y1u  = (uint*)regB;
  float* r2   = (float*)regB;

  // r1 and z both live in d_out; k_aggr2 fully overwrites d_out at the end.
  float* r1 = (float*)d_out;
  float* z  = (float*)d_out;

  const int nb = (NN + 255) / 256;
  const int ab = (NN * 64 + 255) / 256;

  dim3 hg(HB, 2);
  c_hist<<<hg, 256, 0, stream>>>(pe, ne, part_hist);
  dim3 cg(256, 2);
  c_colscan<<<cg, 256, 0, stream>>>(part_hist, tot);
  c_basescan<<<1, 512, 0, stream>>>(tot, base);
  c_scatter<<<hg, 256, 0, stream>>>(pe, ne, part_hist, base, partP, partN);
  c_bucket<<<2 * NBKT + 2 * NBLK, 512, 0, stream>>>(
      partP, partN, base, row_p, row_n, col_p, col_n,
      x, w1_pl, w1_pr, b1_p, w1_nl, w1_nr, b1_n, y1u, r1);

  k_aggr1<<<ab, 256, 0, stream>>>(y1u, row_p, col_p, row_n, col_n, r1, z);

  dim3 g2(nb, 6);
  k_mid<<<g2, 256, 0, stream>>>(z, w2_pl, w2_pr, b2_p, w2_nl, w2_nr, b2_n,
                                u_pos, u_neg, r2);

  k_aggr2<<<ab, 256, 0, stream>>>(u_pos, u_neg, row_p, col_p, row_n, col_n, r2,
                                  (float*)d_out);
}